// Round 4
// baseline (179842.627 us; speedup 1.0000x reference)
//
#include <hip/hip_runtime.h>
#include <stdint.h>

// R4: weights resident in AGPRs via explicit v_accvgpr_write/read inline asm.
//     "a"-class virtual registers have no competing users -> regalloc cannot
//     spill them the way it spilled the "v"-class weight arrays in R2/R3.

#define S_LEN 8192
#define HID   1024
#define DIN0  256
#define NL    4
#define NCU_L 64        // CUs per layer
#define NTHR  512       // threads per block (8 waves)
#define NWAVE 8
#define SPL0  80        // weight dwords per lane per wave, layer 0 (8*80*2 = 1280 cols)
#define SPL   128       // layers 1-3 (8*128*2 = 2048 cols)

typedef _Float16 half2v __attribute__((ext_vector_type(2)));
typedef uint32_t v4u   __attribute__((ext_vector_type(4)));

#if defined(__has_builtin)
#if __has_builtin(__builtin_amdgcn_fdot2)
#define HAVE_FDOT2 1
#endif
#endif

__device__ __forceinline__ float dot2acc(uint32_t w, uint32_t x, float acc) {
#ifdef HAVE_FDOT2
    return __builtin_amdgcn_fdot2(__builtin_bit_cast(half2v, w),
                                  __builtin_bit_cast(half2v, x), acc, false);
#else
    half2v hw = __builtin_bit_cast(half2v, w);
    half2v hx = __builtin_bit_cast(half2v, x);
    return acc + (float)hw.x * (float)hx.x + (float)hw.y * (float)hx.y;
#endif
}

// ---- workspace layout (dwords/bytes) ----
constexpr size_t X0_DW  = (size_t)S_LEN * DIN0 / 2;                 // 4 MB
constexpr size_t X0B    = X0_DW * 4;
constexpr size_t HB     = (size_t)NL * S_LEN * HID * 2;             // 64 MB
constexpr size_t W0_DW  = (size_t)NCU_L * NWAVE * SPL0 * 64;
constexpr size_t WL_DW  = (size_t)NCU_L * NWAVE * SPL * 64;
constexpr size_t WB     = (W0_DW + 3 * WL_DW) * 4;                  // ~58 MB
constexpr size_t FLAG_N = (size_t)NL * NCU_L + 1;                   // +1 abort flag
constexpr size_t TOTAL_WS = X0B + HB + WB + FLAG_N * 4;

// ---------------- pre-kernels ----------------

__global__ void conv_x_kernel(const float* __restrict__ x, uint32_t* __restrict__ dst) {
    int i = blockIdx.x * 256 + threadIdx.x;   // exactly X0_DW threads
    float v0 = x[2 * i], v1 = x[2 * i + 1];
    half2v h = {(_Float16)v0, (_Float16)v1};
    dst[i] = __builtin_bit_cast(uint32_t, h);
}

// dst layout: [k(64)][wave(8)][c4(SP/4)][lane(64)][e(4)] — per-thread 16B chunks.
__global__ void pack_weights_kernel(const float* __restrict__ wih, const float* __restrict__ whh,
                                    int din, int SP, uint32_t* __restrict__ dst) {
    int i = blockIdx.x * 256 + threadIdx.x;   // exactly 64*8*SP*64 threads
    const int SP4 = SP / 4;
    int e = i & 3;
    int q = i >> 2;
    int l = q & 63; q >>= 6;
    int c4 = q % SP4; q /= SP4;
    int w = q & 7;
    int k = q >> 3;
    int c = c4 * 4 + e;                        // dword index within this wave's slice
    int row = (l >> 4) * HID + k * 16 + (l & 15);
    int col = w * (2 * SP) + 2 * c;            // half-index into [x(din) | h(HID)]
    float v0 = (col < din) ? wih[(size_t)row * din + col] : whh[(size_t)row * HID + (col - din)];
    float v1 = (col + 1 < din) ? wih[(size_t)row * din + col + 1] : whh[(size_t)row * HID + (col + 1 - din)];
    half2v h = {(_Float16)v0, (_Float16)v1};
    dst[i] = __builtin_bit_cast(uint32_t, h);
}

__global__ void init_misc_kernel(int* __restrict__ flags, int n, float* __restrict__ out,
                                 const float* __restrict__ fcb) {
    int i = blockIdx.x * 256 + threadIdx.x;
    if (i < n) flags[i] = 0;
    if (i == 0) out[0] = fcb[0];
}

// ---------------- persistent LSTM kernel ----------------

__device__ __forceinline__ float fsigmoid(float x) { return 1.f / (1.f + __expf(-x)); }
__device__ __forceinline__ float ftanh_c(float x) {   // input pre-clamped |x|<=15
    float e = __expf(-2.f * x);
    return (1.f - e) / (1.f + e);
}

template <int SP, int DIN>
__device__ __forceinline__ void run_layer(
    int k,
    const uint32_t* __restrict__ xsrc,   // packed fp16 pairs, row stride DIN/2 dwords
    _Float16* hh_own,                    // own-layer h history (half), row stride HID
    const uint32_t* hh_dw_own,           // dword view of same buffer
    const uint32_t* __restrict__ wsrc,   // this block's packed weights
    const float* __restrict__ bias,
    const float* __restrict__ fcw,
    float* out,
    int* ownf, int* upf, int* abortf, bool doFC)
{
    constexpr int SP4  = SP / 4;
    constexpr int XDW  = DIN / 2;            // staged x dwords
    constexpr int INDW = XDW + HID / 2;      // total staged dwords
    static_assert(INDW == NWAVE * SP, "layout");

    __shared__ alignas(16) uint32_t in_lds[INDW];
    __shared__ float red[NWAVE][64];

    const int tid  = threadIdx.x;
    const int wave = tid >> 6;
    const int lane = tid & 63;

    // ---- load weight slice and park it in AGPRs (SP regs/thread) ----
    uint32_t aw[SP];                         // each element -> one AGPR
    {
        const uint32_t* wb = wsrc + (size_t)wave * SP * 64 + lane * 4;
#pragma unroll
        for (int c4 = 0; c4 < SP4; ++c4) {
            v4u tv = *(const v4u*)(wb + (size_t)c4 * 256);
            asm volatile("v_accvgpr_write_b32 %0, %1" : "=a"(aw[4 * c4 + 0]) : "v"(tv[0]));
            asm volatile("v_accvgpr_write_b32 %0, %1" : "=a"(aw[4 * c4 + 1]) : "v"(tv[1]));
            asm volatile("v_accvgpr_write_b32 %0, %1" : "=a"(aw[4 * c4 + 2]) : "v"(tv[2]));
            asm volatile("v_accvgpr_write_b32 %0, %1" : "=a"(aw[4 * c4 + 3]) : "v"(tv[3]));
        }
    }

    float bval = 0.f, fcv = 0.f;
    if (wave == 0) {
        bval = bias[(lane >> 4) * HID + k * 16 + (lane & 15)];
        if (lane < 16) fcv = fcw[k * 16 + lane];
    }
    float cst = 0.f, hval = 0.f;

    for (int t = 0; t < S_LEN; ++t) {
        // ---- wave0 polls readiness flags; other waves park at barrier ----
        if (wave == 0) {
            int it = 0;
            for (;;) {
                int ok = 1;
                if (upf)
                    ok &= (__hip_atomic_load(upf + lane, __ATOMIC_RELAXED,
                                             __HIP_MEMORY_SCOPE_AGENT) >= t + 1);
                if (t)
                    ok &= (__hip_atomic_load(ownf + lane, __ATOMIC_RELAXED,
                                             __HIP_MEMORY_SCOPE_AGENT) >= t);
                if (__all(ok)) break;
                if ((++it & 63) == 0) {
                    if (__hip_atomic_load(abortf, __ATOMIC_RELAXED, __HIP_MEMORY_SCOPE_AGENT)) break;
                    if (it > (1 << 22)) {
                        __hip_atomic_store(abortf, 1, __ATOMIC_RELAXED, __HIP_MEMORY_SCOPE_AGENT);
                        break;
                    }
                }
            }
        }
        __syncthreads();
        __builtin_amdgcn_fence(__ATOMIC_ACQUIRE, "agent");

        // ---- stage x_t || h_{t-1} into LDS (8B per thread) ----
        {
            const int dw = tid * 2;
            if (dw < XDW) {
                *(int2*)&in_lds[dw] = *(const int2*)&xsrc[(size_t)t * XDW + dw];
            } else if (dw < INDW) {
                int2 v = {0, 0};
                if (t) v = *(const int2*)&hh_dw_own[(size_t)(t - 1) * (HID / 2) + (dw - XDW)];
                *(int2*)&in_lds[dw] = v;
            }
        }
        __syncthreads();

        // ---- dot: lane = gate row, wave = column slice; x broadcast from LDS ----
        const uint32_t* wi = in_lds + wave * SP;
        float a0 = 0, a1 = 0, a2 = 0, a3 = 0, a4 = 0, a5 = 0, a6 = 0, a7 = 0;
#pragma unroll
        for (int c4 = 0; c4 < SP4; c4 += 2) {
            v4u x0 = *(const v4u*)&wi[c4 * 4];
            v4u x1 = *(const v4u*)&wi[c4 * 4 + 4];
            uint32_t w0, w1, w2, w3, w4, w5, w6, w7;
            asm volatile("v_accvgpr_read_b32 %0, %1" : "=v"(w0) : "a"(aw[4 * c4 + 0]));
            asm volatile("v_accvgpr_read_b32 %0, %1" : "=v"(w1) : "a"(aw[4 * c4 + 1]));
            asm volatile("v_accvgpr_read_b32 %0, %1" : "=v"(w2) : "a"(aw[4 * c4 + 2]));
            asm volatile("v_accvgpr_read_b32 %0, %1" : "=v"(w3) : "a"(aw[4 * c4 + 3]));
            asm volatile("v_accvgpr_read_b32 %0, %1" : "=v"(w4) : "a"(aw[4 * c4 + 4]));
            asm volatile("v_accvgpr_read_b32 %0, %1" : "=v"(w5) : "a"(aw[4 * c4 + 5]));
            asm volatile("v_accvgpr_read_b32 %0, %1" : "=v"(w6) : "a"(aw[4 * c4 + 6]));
            asm volatile("v_accvgpr_read_b32 %0, %1" : "=v"(w7) : "a"(aw[4 * c4 + 7]));
            a0 = dot2acc(w0, x0[0], a0);
            a1 = dot2acc(w1, x0[1], a1);
            a2 = dot2acc(w2, x0[2], a2);
            a3 = dot2acc(w3, x0[3], a3);
            a4 = dot2acc(w4, x1[0], a4);
            a5 = dot2acc(w5, x1[1], a5);
            a6 = dot2acc(w6, x1[2], a6);
            a7 = dot2acc(w7, x1[3], a7);
        }
        red[wave][lane] = ((a0 + a1) + (a2 + a3)) + ((a4 + a5) + (a6 + a7));
        __syncthreads();

        // ---- wave0: reduce, gates, state update, publish ----
        if (wave == 0) {
            float p = ((red[0][lane] + red[1][lane]) + (red[2][lane] + red[3][lane])) +
                      ((red[4][lane] + red[5][lane]) + (red[6][lane] + red[7][lane])) + bval;
            p = fminf(15.f, fmaxf(-15.f, p));
            const int j = lane & 15;
            float pi = __shfl(p, j);
            float pf = __shfl(p, j + 16);
            float pg = __shfl(p, j + 32);
            float po = __shfl(p, j + 48);
            if (lane < 16) {
                float ig = fsigmoid(pi);
                float fg = fsigmoid(pf);
                float gg = ftanh_c(pg);
                float og = fsigmoid(po);
                cst = fg * cst + ig * gg;
                float c2 = fminf(15.f, fmaxf(-15.f, cst));
                hval = og * ftanh_c(c2);
                hh_own[(size_t)t * HID + k * 16 + lane] = (_Float16)hval;
            }
            __builtin_amdgcn_fence(__ATOMIC_RELEASE, "agent");
            if (lane == 0)
                __hip_atomic_store(ownf + k, t + 1, __ATOMIC_RELAXED, __HIP_MEMORY_SCOPE_AGENT);
        }
    }

    // ---- final FC (layer 3): y = fc_w . h_last + fc_b ----
    if (doFC && wave == 0) {
        float p = (lane < 16) ? fcv * hval : 0.f;
#pragma unroll
        for (int o = 8; o; o >>= 1) p += __shfl_xor(p, o);
        if (lane == 0) atomicAdd(out, p);
    }
}

__global__ __launch_bounds__(NTHR, 2) void lstm_persistent(
    const uint32_t* __restrict__ x0p,
    _Float16* hh,
    const uint32_t* __restrict__ wp,
    const float* __restrict__ b0, const float* __restrict__ b1,
    const float* __restrict__ b2, const float* __restrict__ b3,
    const float* __restrict__ fcw, float* out,
    int* flags, int* abortf)
{
    const int bid = blockIdx.x;
    const int xcd = bid & 7;
    const int layer = xcd >> 1;                    // 2 XCDs per layer
    const int k = ((bid >> 3) << 1) | (xcd & 1);   // 0..63 within layer

    const float* bias = (layer == 0) ? b0 : (layer == 1) ? b1 : (layer == 2) ? b2 : b3;
    int* ownf = flags + layer * NCU_L;
    int* upf  = layer ? (flags + (layer - 1) * NCU_L) : nullptr;

    _Float16* hh_own = hh + (size_t)layer * S_LEN * HID;
    const uint32_t* hh_dw_own = (const uint32_t*)hh + (size_t)layer * S_LEN * (HID / 2);

    if (layer == 0) {
        const uint32_t* wsrc = wp + (size_t)k * NWAVE * SPL0 * 64;
        run_layer<SPL0, DIN0>(k, x0p, hh_own, hh_dw_own, wsrc, bias, fcw, out,
                              ownf, nullptr, abortf, false);
    } else {
        const uint32_t* xsrc = (const uint32_t*)hh + (size_t)(layer - 1) * S_LEN * (HID / 2);
        const uint32_t* wsrc = wp + W0_DW + (size_t)(layer - 1) * WL_DW + (size_t)k * NWAVE * SPL * 64;
        run_layer<SPL, HID>(k, xsrc, hh_own, hh_dw_own, wsrc, bias, fcw, out,
                            ownf, upf, abortf, layer == 3);
    }
}

// ---------------- host launcher ----------------

extern "C" void kernel_launch(void* const* d_in, const int* in_sizes, int n_in,
                              void* d_out, int out_size, void* d_ws, size_t ws_size,
                              hipStream_t stream) {
    const float* seq  = (const float*)d_in[0];
    const float* wih0 = (const float*)d_in[1];
    const float* whh0 = (const float*)d_in[2];
    const float* b0   = (const float*)d_in[3];
    const float* wih1 = (const float*)d_in[4];
    const float* whh1 = (const float*)d_in[5];
    const float* b1   = (const float*)d_in[6];
    const float* wih2 = (const float*)d_in[7];
    const float* whh2 = (const float*)d_in[8];
    const float* b2   = (const float*)d_in[9];
    const float* wih3 = (const float*)d_in[10];
    const float* whh3 = (const float*)d_in[11];
    const float* b3   = (const float*)d_in[12];
    const float* fcw  = (const float*)d_in[13];
    const float* fcb  = (const float*)d_in[14];
    float* out = (float*)d_out;

    if (ws_size < TOTAL_WS) return;

    uint8_t* ws = (uint8_t*)d_ws;
    uint32_t* x0p = (uint32_t*)ws;
    _Float16* hh  = (_Float16*)(ws + X0B);
    uint32_t* wp  = (uint32_t*)(ws + X0B + HB);
    int* flags    = (int*)(ws + X0B + HB + WB);
    int* abortf   = flags + NL * NCU_L;

    conv_x_kernel<<<(int)(X0_DW / 256), 256, 0, stream>>>(seq, x0p);
    pack_weights_kernel<<<(int)(W0_DW / 256), 256, 0, stream>>>(wih0, whh0, DIN0, SPL0, wp);
    pack_weights_kernel<<<(int)(WL_DW / 256), 256, 0, stream>>>(wih1, whh1, HID, SPL, wp + W0_DW);
    pack_weights_kernel<<<(int)(WL_DW / 256), 256, 0, stream>>>(wih2, whh2, HID, SPL, wp + W0_DW + WL_DW);
    pack_weights_kernel<<<(int)(WL_DW / 256), 256, 0, stream>>>(wih3, whh3, HID, SPL, wp + W0_DW + 2 * WL_DW);
    init_misc_kernel<<<(int)((FLAG_N + 255) / 256), 256, 0, stream>>>(flags, (int)FLAG_N, out, fcb);

    // persistent pipelined recurrence: 256 blocks (1/CU), 512 threads
    lstm_persistent<<<256, NTHR, 0, stream>>>(x0p, hh, wp, b0, b1, b2, b3, fcw, out, flags, abortf);
}

// Round 5
// 29676.465 us; speedup vs baseline: 6.0601x; 6.0601x over previous
//
#include <hip/hip_runtime.h>
#include <stdint.h>

// R5: NO per-step fences. All cross-CU traffic via agent-scope (sc1, L2-bypass)
//     atomic loads/stores; hand-rolled release = s_waitcnt(0) + relaxed flag store.
//     h history in an L3-hot ring buffer. Weights in 32 NAMED v4u registers
//     (no arrays -> no scratch demotion), sched_barrier(0) to cap pressure.

#define S_LEN 8192
#define HID   1024
#define DIN0  256
#define NL    4
#define NCU_L 64
#define NTHR  512
#define NWAVE 8
#define SP    128          // weight dwords per lane per wave (uniform, L0 zero-padded)
#define RING  1024
#define RMASK (RING - 1)

typedef _Float16 half2v __attribute__((ext_vector_type(2)));
typedef uint32_t v4u   __attribute__((ext_vector_type(4)));

#if defined(__has_builtin)
#if __has_builtin(__builtin_amdgcn_fdot2)
#define HAVE_FDOT2 1
#endif
#endif

__device__ __forceinline__ float dot2acc(uint32_t w, uint32_t x, float acc) {
#ifdef HAVE_FDOT2
    return __builtin_amdgcn_fdot2(__builtin_bit_cast(half2v, w),
                                  __builtin_bit_cast(half2v, x), acc, false);
#else
    half2v hw = __builtin_bit_cast(half2v, w);
    half2v hx = __builtin_bit_cast(half2v, x);
    return acc + (float)hw.x * (float)hx.x + (float)hw.y * (float)hx.y;
#endif
}

#define ALOAD(p)     __hip_atomic_load((p), __ATOMIC_RELAXED, __HIP_MEMORY_SCOPE_AGENT)
#define ASTORE(p, v) __hip_atomic_store((p), (v), __ATOMIC_RELAXED, __HIP_MEMORY_SCOPE_AGENT)

// ---- workspace layout ----
constexpr size_t X0_DW   = (size_t)S_LEN * (DIN0 / 2);            // 1M dw = 4 MB
constexpr size_t X0B     = X0_DW * 4;
constexpr size_t RING_DW = (size_t)NL * RING * (HID / 2);         // 2M dw = 8 MB
constexpr size_t RINGB   = RING_DW * 4;
constexpr size_t WK_DW   = (size_t)NWAVE * SP * 64;               // 65536 dw per block
constexpr size_t WL_DW   = (size_t)NCU_L * WK_DW;                 // per layer
constexpr size_t WB      = (size_t)NL * WL_DW * 4;                // ~67 MB
constexpr size_t FLAG_N  = (size_t)NL * NCU_L + 1;                // +1 abort
constexpr size_t TOTAL_WS = X0B + RINGB + WB + FLAG_N * 4;

// ---------------- pre-kernels ----------------

__global__ void conv_x_kernel(const float* __restrict__ x, uint32_t* __restrict__ dst) {
    int i = blockIdx.x * 256 + threadIdx.x;   // exactly X0_DW threads
    float v0 = x[2 * i], v1 = x[2 * i + 1];
    half2v h = {(_Float16)v0, (_Float16)v1};
    dst[i] = __builtin_bit_cast(uint32_t, h);
}

// dst layout: [k(64)][wave(8)][c4(32)][lane(64)][e(4)].
// Column space (halves): [0,1024) = x region (cols >= din are zero-padded),
//                        [1024,2048) = h region.
__global__ void pack_weights_kernel(const float* __restrict__ wih, const float* __restrict__ whh,
                                    int din, uint32_t* __restrict__ dst) {
    int i = blockIdx.x * 256 + threadIdx.x;   // exactly WL_DW threads
    int e = i & 3;  int q = i >> 2;
    int l = q & 63; q >>= 6;
    int c4 = q & 31; q >>= 5;
    int w = q & 7;  int k = q >> 3;
    int c = 4 * c4 + e;
    int col = w * 256 + 2 * c;                // half col in [0,2048)
    int row = (l >> 4) * HID + k * 16 + (l & 15);
    float v0, v1;
    {
        int hc = col;
        v0 = (hc < 1024) ? ((hc < din) ? wih[(size_t)row * din + hc] : 0.f)
                         : whh[(size_t)row * HID + (hc - 1024)];
        hc = col + 1;
        v1 = (hc < 1024) ? ((hc < din) ? wih[(size_t)row * din + hc] : 0.f)
                         : whh[(size_t)row * HID + (hc - 1024)];
    }
    half2v h = {(_Float16)v0, (_Float16)v1};
    dst[i] = __builtin_bit_cast(uint32_t, h);
}

__global__ void init_misc_kernel(int* __restrict__ flags, int n, float* __restrict__ out,
                                 const float* __restrict__ fcb) {
    int i = blockIdx.x * 256 + threadIdx.x;
    if (i < n) flags[i] = 0;
    if (i == 0) out[0] = fcb[0];
}

// ---------------- persistent LSTM kernel ----------------

__device__ __forceinline__ float fsigmoid(float x) { return 1.f / (1.f + __expf(-x)); }
__device__ __forceinline__ float ftanh_c(float x) {
    float e = __expf(-2.f * x);
    return (1.f - e) / (1.f + e);
}

#define REP32(M) M(0) M(1) M(2) M(3) M(4) M(5) M(6) M(7) M(8) M(9) M(10) M(11) \
                 M(12) M(13) M(14) M(15) M(16) M(17) M(18) M(19) M(20) M(21) M(22) M(23) \
                 M(24) M(25) M(26) M(27) M(28) M(29) M(30) M(31)

__device__ __forceinline__ void run_layer(
    int k, bool isL0,
    const uint32_t* __restrict__ x0p,     // layer 0 input (packed halves)
    const uint32_t* up_ring,              // upstream layer ring (null for L0)
    uint32_t* own_ring,                   // own layer ring
    const uint32_t* __restrict__ wsrc,    // this block's packed weights
    const float* __restrict__ bias,
    const float* __restrict__ fcw,
    float* out,
    int* ownf, int* upf, int* dnf, int* abortf, bool doFC)
{
    __shared__ alignas(16) uint32_t in_lds[NWAVE * SP];   // 1024 dw = 4 KB
    __shared__ float red[NWAVE][64];

    const int tid  = threadIdx.x;
    const int wave = tid >> 6;
    const int lane = tid & 63;

    // ---- weight slice: 32 NAMED v4u values (128 VGPRs), no arrays ----
    const uint32_t* wb = wsrc + (size_t)wave * (SP * 64) + lane * 4;
#define WLOAD(i) v4u W##i = *(const v4u*)(wb + (size_t)(i) * 256);
    REP32(WLOAD)
#undef WLOAD

    float bval = 0.f, fcv = 0.f;
    if (wave == 0) {
        bval = bias[(lane >> 4) * HID + k * 16 + (lane & 15)];
        if (lane < 16) fcv = fcw[k * 16 + lane];
    }
    float cst = 0.f, hval = 0.f;

    for (int t = 0; t < S_LEN; ++t) {
        // ---- wave0 polls flags (bypassing atomic loads); no fences ----
        if (wave == 0) {
            int it = 0;
            for (;;) {
                int ok = 1;
                if (upf) ok &= (ALOAD(upf + lane) >= t + 1);
                if (t)   ok &= (ALOAD(ownf + lane) >= t);
                if (dnf && t >= RING) ok &= (ALOAD(dnf + lane) >= t - RING + 1);
                if (__all(ok)) break;
                if ((++it & 63) == 0) {
                    if (ALOAD(abortf)) break;
                    if (it > (1 << 22)) { ASTORE(abortf, 1); break; }
                }
            }
        }
        __syncthreads();

        // ---- stage [x_pad(512dw) | h_{t-1}(512dw)] into LDS; 2 dw/thread ----
        {
            const int dw = tid * 2;
            uint32_t v0, v1;
            if (dw < 512) {
                if (isL0) {
                    v0 = (dw < 128) ? x0p[(size_t)t * 128 + dw] : 0u;
                    v1 = (dw < 128) ? x0p[(size_t)t * 128 + dw + 1] : 0u;
                } else {
                    const uint32_t* s = up_ring + (size_t)(t & RMASK) * 512;
                    v0 = ALOAD(s + dw);
                    v1 = ALOAD(s + dw + 1);
                }
            } else {
                const int d2 = dw - 512;
                if (t) {
                    const uint32_t* s = own_ring + (size_t)((t - 1) & RMASK) * 512;
                    v0 = ALOAD(s + d2);
                    v1 = ALOAD(s + d2 + 1);
                } else { v0 = 0u; v1 = 0u; }
            }
            in_lds[dw] = v0;
            in_lds[dw + 1] = v1;
        }
        __syncthreads();

        // ---- dot: lane = gate row, wave = 256-half column slice ----
        const uint32_t* wi = in_lds + wave * SP;
        float a0 = 0, a1 = 0, a2 = 0, a3 = 0;
#define DOT(i) { v4u x_ = *(const v4u*)&wi[4 * (i)];            \
        a0 = dot2acc(W##i[0], x_[0], a0);                       \
        a1 = dot2acc(W##i[1], x_[1], a1);                       \
        a2 = dot2acc(W##i[2], x_[2], a2);                       \
        a3 = dot2acc(W##i[3], x_[3], a3); }
        DOT(0) DOT(1) DOT(2) DOT(3)
        __builtin_amdgcn_sched_barrier(0);
        DOT(4) DOT(5) DOT(6) DOT(7)
        __builtin_amdgcn_sched_barrier(0);
        DOT(8) DOT(9) DOT(10) DOT(11)
        __builtin_amdgcn_sched_barrier(0);
        DOT(12) DOT(13) DOT(14) DOT(15)
        __builtin_amdgcn_sched_barrier(0);
        DOT(16) DOT(17) DOT(18) DOT(19)
        __builtin_amdgcn_sched_barrier(0);
        DOT(20) DOT(21) DOT(22) DOT(23)
        __builtin_amdgcn_sched_barrier(0);
        DOT(24) DOT(25) DOT(26) DOT(27)
        __builtin_amdgcn_sched_barrier(0);
        DOT(28) DOT(29) DOT(30) DOT(31)
#undef DOT
        red[wave][lane] = (a0 + a1) + (a2 + a3);
        __syncthreads();

        // ---- wave0: reduce, gates, publish (bypassing stores, no fences) ----
        if (wave == 0) {
            float p = ((red[0][lane] + red[1][lane]) + (red[2][lane] + red[3][lane])) +
                      ((red[4][lane] + red[5][lane]) + (red[6][lane] + red[7][lane])) + bval;
            p = fminf(15.f, fmaxf(-15.f, p));
            const int j = lane & 15;
            float pi = __shfl(p, j);
            float pf = __shfl(p, j + 16);
            float pg = __shfl(p, j + 32);
            float po = __shfl(p, j + 48);
            if (lane < 16) {
                float ig = fsigmoid(pi);
                float fg = fsigmoid(pf);
                float gg = ftanh_c(pg);
                float og = fsigmoid(po);
                cst = fg * cst + ig * gg;
                float c2 = fminf(15.f, fmaxf(-15.f, cst));
                hval = og * ftanh_c(c2);
            }
            // pack 16 halves -> 8 dwords; lanes 0..7 store write-through
            float h0 = __shfl(hval, (2 * lane) & 63);
            float h1 = __shfl(hval, (2 * lane + 1) & 63);
            half2v hp = {(_Float16)h0, (_Float16)h1};
            uint32_t packed = __builtin_bit_cast(uint32_t, hp);
            if (lane < 8)
                ASTORE(own_ring + (size_t)(t & RMASK) * 512 + k * 8 + lane, packed);
            __builtin_amdgcn_s_waitcnt(0);   // hand-rolled release: data at L3
            if (lane == 0) ASTORE(ownf + k, t + 1);
        }
    }

    // ---- final FC (layer 3): y = fc_w . h_last + fc_b ----
    if (doFC && wave == 0) {
        float p = (lane < 16) ? fcv * hval : 0.f;
#pragma unroll
        for (int o = 8; o; o >>= 1) p += __shfl_xor(p, o);
        if (lane == 0) atomicAdd(out, p);
    }
}

__global__ __launch_bounds__(NTHR, 2) void lstm_persistent(
    const uint32_t* __restrict__ x0p,
    uint32_t* ring,
    const uint32_t* __restrict__ wp,
    const float* __restrict__ b0, const float* __restrict__ b1,
    const float* __restrict__ b2, const float* __restrict__ b3,
    const float* __restrict__ fcw, float* out,
    int* flags, int* abortf)
{
    const int bid = blockIdx.x;
    const int xcd = bid & 7;
    const int layer = xcd >> 1;                    // 2 XCDs per layer
    const int k = ((bid >> 3) << 1) | (xcd & 1);   // 0..63 within layer

    const float* bias = (layer == 0) ? b0 : (layer == 1) ? b1 : (layer == 2) ? b2 : b3;
    int* ownf = flags + layer * NCU_L;
    int* upf  = layer ? (flags + (layer - 1) * NCU_L) : nullptr;
    int* dnf  = (layer < 3) ? (flags + (layer + 1) * NCU_L) : nullptr;

    uint32_t* own_ring = ring + (size_t)layer * RING * 512;
    const uint32_t* up_ring = layer ? (ring + (size_t)(layer - 1) * RING * 512) : nullptr;
    const uint32_t* wsrc = wp + (size_t)layer * WL_DW + (size_t)k * WK_DW;

    run_layer(k, layer == 0, x0p, up_ring, own_ring, wsrc, bias, fcw, out,
              ownf, upf, dnf, abortf, layer == 3);
}

// ---------------- host launcher ----------------

extern "C" void kernel_launch(void* const* d_in, const int* in_sizes, int n_in,
                              void* d_out, int out_size, void* d_ws, size_t ws_size,
                              hipStream_t stream) {
    const float* seq  = (const float*)d_in[0];
    const float* wih0 = (const float*)d_in[1];
    const float* whh0 = (const float*)d_in[2];
    const float* b0   = (const float*)d_in[3];
    const float* wih1 = (const float*)d_in[4];
    const float* whh1 = (const float*)d_in[5];
    const float* b1   = (const float*)d_in[6];
    const float* wih2 = (const float*)d_in[7];
    const float* whh2 = (const float*)d_in[8];
    const float* b2   = (const float*)d_in[9];
    const float* wih3 = (const float*)d_in[10];
    const float* whh3 = (const float*)d_in[11];
    const float* b3   = (const float*)d_in[12];
    const float* fcw  = (const float*)d_in[13];
    const float* fcb  = (const float*)d_in[14];
    float* out = (float*)d_out;

    if (ws_size < TOTAL_WS) return;

    uint8_t* ws = (uint8_t*)d_ws;
    uint32_t* x0p  = (uint32_t*)ws;
    uint32_t* ring = (uint32_t*)(ws + X0B);
    uint32_t* wp   = (uint32_t*)(ws + X0B + RINGB);
    int* flags     = (int*)(ws + X0B + RINGB + WB);
    int* abortf    = flags + NL * NCU_L;

    conv_x_kernel<<<(int)(X0_DW / 256), 256, 0, stream>>>(seq, x0p);
    pack_weights_kernel<<<(int)(WL_DW / 256), 256, 0, stream>>>(wih0, whh0, DIN0, wp);
    pack_weights_kernel<<<(int)(WL_DW / 256), 256, 0, stream>>>(wih1, whh1, HID, wp + WL_DW);
    pack_weights_kernel<<<(int)(WL_DW / 256), 256, 0, stream>>>(wih2, whh2, HID, wp + 2 * WL_DW);
    pack_weights_kernel<<<(int)(WL_DW / 256), 256, 0, stream>>>(wih3, whh3, HID, wp + 3 * WL_DW);
    init_misc_kernel<<<(int)((FLAG_N + 255) / 256), 256, 0, stream>>>(flags, (int)FLAG_N, out, fcb);

    lstm_persistent<<<256, NTHR, 0, stream>>>(x0p, ring, wp, b0, b1, b2, b3, fcw, out, flags, abortf);
}

// Round 6
// 27235.901 us; speedup vs baseline: 6.6031x; 1.0896x over previous
//
#include <hip/hip_runtime.h>
#include <stdint.h>

// R6: weights loaded via asm volatile global_load_dwordx4 -> values are
//     asm-produced, NOT rematerializable; regalloc must keep them in VGPRs
//     (128/thread, budget 256 at launch_bounds(512,2)). Everything else = R5
//     (fence-free bypassing atomics, L3 ring, sched_barrier pressure clamps).
//     Staging upgraded to 64-bit atomic loads + ds_write_b64.

#define S_LEN 8192
#define HID   1024
#define DIN0  256
#define NL    4
#define NCU_L 64
#define NTHR  512
#define NWAVE 8
#define SP    128          // weight dwords per lane per wave (uniform, L0 zero-padded)
#define RING  1024
#define RMASK (RING - 1)

typedef _Float16 half2v __attribute__((ext_vector_type(2)));
typedef uint32_t v4u   __attribute__((ext_vector_type(4)));

#if defined(__has_builtin)
#if __has_builtin(__builtin_amdgcn_fdot2)
#define HAVE_FDOT2 1
#endif
#endif

__device__ __forceinline__ float dot2acc(uint32_t w, uint32_t x, float acc) {
#ifdef HAVE_FDOT2
    return __builtin_amdgcn_fdot2(__builtin_bit_cast(half2v, w),
                                  __builtin_bit_cast(half2v, x), acc, false);
#else
    half2v hw = __builtin_bit_cast(half2v, w);
    half2v hx = __builtin_bit_cast(half2v, x);
    return acc + (float)hw.x * (float)hx.x + (float)hw.y * (float)hx.y;
#endif
}

#define ALOAD(p)      __hip_atomic_load((p), __ATOMIC_RELAXED, __HIP_MEMORY_SCOPE_AGENT)
#define ASTORE(p, v)  __hip_atomic_store((p), (v), __ATOMIC_RELAXED, __HIP_MEMORY_SCOPE_AGENT)

// ---- workspace layout ----
constexpr size_t X0_DW   = (size_t)S_LEN * (DIN0 / 2);            // 1M dw = 4 MB
constexpr size_t X0B     = X0_DW * 4;
constexpr size_t RING_DW = (size_t)NL * RING * (HID / 2);         // 2M dw = 8 MB
constexpr size_t RINGB   = RING_DW * 4;
constexpr size_t WK_DW   = (size_t)NWAVE * SP * 64;               // 65536 dw per block
constexpr size_t WL_DW   = (size_t)NCU_L * WK_DW;                 // per layer
constexpr size_t WB      = (size_t)NL * WL_DW * 4;                // ~67 MB
constexpr size_t FLAG_N  = (size_t)NL * NCU_L + 1;                // +1 abort
constexpr size_t TOTAL_WS = X0B + RINGB + WB + FLAG_N * 4;

// ---------------- pre-kernels ----------------

__global__ void conv_x_kernel(const float* __restrict__ x, uint32_t* __restrict__ dst) {
    int i = blockIdx.x * 256 + threadIdx.x;   // exactly X0_DW threads
    float v0 = x[2 * i], v1 = x[2 * i + 1];
    half2v h = {(_Float16)v0, (_Float16)v1};
    dst[i] = __builtin_bit_cast(uint32_t, h);
}

// dst layout: [k(64)][wave(8)][c4(32)][lane(64)][e(4)].
// Column space (halves): [0,1024) = x region (cols >= din zero-padded),
//                        [1024,2048) = h region.
__global__ void pack_weights_kernel(const float* __restrict__ wih, const float* __restrict__ whh,
                                    int din, uint32_t* __restrict__ dst) {
    int i = blockIdx.x * 256 + threadIdx.x;   // exactly WL_DW threads
    int e = i & 3;  int q = i >> 2;
    int l = q & 63; q >>= 6;
    int c4 = q & 31; q >>= 5;
    int w = q & 7;  int k = q >> 3;
    int c = 4 * c4 + e;
    int col = w * 256 + 2 * c;                // half col in [0,2048)
    int row = (l >> 4) * HID + k * 16 + (l & 15);
    float v0, v1;
    {
        int hc = col;
        v0 = (hc < 1024) ? ((hc < din) ? wih[(size_t)row * din + hc] : 0.f)
                         : whh[(size_t)row * HID + (hc - 1024)];
        hc = col + 1;
        v1 = (hc < 1024) ? ((hc < din) ? wih[(size_t)row * din + hc] : 0.f)
                         : whh[(size_t)row * HID + (hc - 1024)];
    }
    half2v h = {(_Float16)v0, (_Float16)v1};
    dst[i] = __builtin_bit_cast(uint32_t, h);
}

__global__ void init_misc_kernel(int* __restrict__ flags, int n, float* __restrict__ out,
                                 const float* __restrict__ fcb) {
    int i = blockIdx.x * 256 + threadIdx.x;
    if (i < n) flags[i] = 0;
    if (i == 0) out[0] = fcb[0];
}

// ---------------- persistent LSTM kernel ----------------

__device__ __forceinline__ float fsigmoid(float x) { return 1.f / (1.f + __expf(-x)); }
__device__ __forceinline__ float ftanh_c(float x) {
    float e = __expf(-2.f * x);
    return (1.f - e) / (1.f + e);
}

#define REP32(M) M(0) M(1) M(2) M(3) M(4) M(5) M(6) M(7) M(8) M(9) M(10) M(11) \
                 M(12) M(13) M(14) M(15) M(16) M(17) M(18) M(19) M(20) M(21) M(22) M(23) \
                 M(24) M(25) M(26) M(27) M(28) M(29) M(30) M(31)

__device__ __forceinline__ void run_layer(
    int k, bool isL0,
    const uint32_t* __restrict__ x0p,     // layer 0 input (packed halves)
    const uint32_t* up_ring,              // upstream layer ring (null for L0)
    uint32_t* own_ring,                   // own layer ring
    const uint32_t* __restrict__ wsrc,    // this block's packed weights
    const float* __restrict__ bias,
    const float* __restrict__ fcw,
    float* out,
    int* ownf, int* upf, int* dnf, int* abortf, bool doFC)
{
    __shared__ alignas(16) uint32_t in_lds[NWAVE * SP];   // 1024 dw = 4 KB
    __shared__ float red[NWAVE][64];

    const int tid  = threadIdx.x;
    const int wave = tid >> 6;
    const int lane = tid & 63;

    // ---- weight slice: 32 v4u via asm volatile loads -> non-rematerializable,
    //      must stay register-resident (or spill to scratch; remat is impossible).
    const uint32_t* wb = wsrc + (size_t)wave * (SP * 64) + lane * 4;
#define WLOAD(i) v4u W##i; { const uint32_t* a_ = wb + (size_t)(i) * 256;        \
        asm volatile("global_load_dwordx4 %0, %1, off\n\ts_waitcnt vmcnt(0)"     \
                     : "=v"(W##i) : "v"(a_) : "memory"); }
    REP32(WLOAD)
#undef WLOAD

    float bval = 0.f, fcv = 0.f;
    if (wave == 0) {
        bval = bias[(lane >> 4) * HID + k * 16 + (lane & 15)];
        if (lane < 16) fcv = fcw[k * 16 + lane];
    }
    float cst = 0.f, hval = 0.f;

    for (int t = 0; t < S_LEN; ++t) {
        // ---- wave0 polls flags (bypassing atomic loads); no fences ----
        if (wave == 0) {
            int it = 0;
            for (;;) {
                int ok = 1;
                if (upf) ok &= (ALOAD(upf + lane) >= t + 1);
                if (t)   ok &= (ALOAD(ownf + lane) >= t);
                if (dnf && t >= RING) ok &= (ALOAD(dnf + lane) >= t - RING + 1);
                if (__all(ok)) break;
                if ((++it & 63) == 0) {
                    if (ALOAD(abortf)) break;
                    if (it > (1 << 22)) { ASTORE(abortf, 1); break; }
                }
            }
        }
        __syncthreads();

        // ---- stage [x_pad(512dw) | h_{t-1}(512dw)] into LDS; 1x u64 per thread ----
        {
            const int dw = tid * 2;
            uint64_t v = 0;
            if (dw < 512) {
                if (isL0) {
                    if (dw < 128) v = *(const uint64_t*)(x0p + (size_t)t * 128 + dw);
                } else {
                    v = ALOAD((const uint64_t*)(up_ring + (size_t)(t & RMASK) * 512) + tid);
                }
            } else if (t) {
                v = ALOAD((const uint64_t*)(own_ring + (size_t)((t - 1) & RMASK) * 512) + (tid - 256));
            }
            *(uint64_t*)&in_lds[dw] = v;
        }
        __syncthreads();

        // ---- dot: lane = gate row, wave = 256-half column slice ----
        const uint32_t* wi = in_lds + wave * SP;
        float a0 = 0, a1 = 0, a2 = 0, a3 = 0;
#define DOT(i) { v4u x_ = *(const v4u*)&wi[4 * (i)];            \
        a0 = dot2acc(W##i[0], x_[0], a0);                       \
        a1 = dot2acc(W##i[1], x_[1], a1);                       \
        a2 = dot2acc(W##i[2], x_[2], a2);                       \
        a3 = dot2acc(W##i[3], x_[3], a3); }
        DOT(0) DOT(1) DOT(2) DOT(3)
        __builtin_amdgcn_sched_barrier(0);
        DOT(4) DOT(5) DOT(6) DOT(7)
        __builtin_amdgcn_sched_barrier(0);
        DOT(8) DOT(9) DOT(10) DOT(11)
        __builtin_amdgcn_sched_barrier(0);
        DOT(12) DOT(13) DOT(14) DOT(15)
        __builtin_amdgcn_sched_barrier(0);
        DOT(16) DOT(17) DOT(18) DOT(19)
        __builtin_amdgcn_sched_barrier(0);
        DOT(20) DOT(21) DOT(22) DOT(23)
        __builtin_amdgcn_sched_barrier(0);
        DOT(24) DOT(25) DOT(26) DOT(27)
        __builtin_amdgcn_sched_barrier(0);
        DOT(28) DOT(29) DOT(30) DOT(31)
#undef DOT
        red[wave][lane] = (a0 + a1) + (a2 + a3);
        __syncthreads();

        // ---- wave0: reduce, gates, publish (bypassing stores, no fences) ----
        if (wave == 0) {
            float p = ((red[0][lane] + red[1][lane]) + (red[2][lane] + red[3][lane])) +
                      ((red[4][lane] + red[5][lane]) + (red[6][lane] + red[7][lane])) + bval;
            p = fminf(15.f, fmaxf(-15.f, p));
            const int j = lane & 15;
            float pi = __shfl(p, j);
            float pf = __shfl(p, j + 16);
            float pg = __shfl(p, j + 32);
            float po = __shfl(p, j + 48);
            if (lane < 16) {
                float ig = fsigmoid(pi);
                float fg = fsigmoid(pf);
                float gg = ftanh_c(pg);
                float og = fsigmoid(po);
                cst = fg * cst + ig * gg;
                float c2 = fminf(15.f, fmaxf(-15.f, cst));
                hval = og * ftanh_c(c2);
            }
            // pack 16 halves -> 8 dwords; lanes 0..7 store write-through
            float h0 = __shfl(hval, (2 * lane) & 63);
            float h1 = __shfl(hval, (2 * lane + 1) & 63);
            half2v hp = {(_Float16)h0, (_Float16)h1};
            uint32_t packed = __builtin_bit_cast(uint32_t, hp);
            if (lane < 8)
                ASTORE(own_ring + (size_t)(t & RMASK) * 512 + k * 8 + lane, packed);
            __builtin_amdgcn_s_waitcnt(0);   // hand-rolled release: data at L3
            if (lane == 0) ASTORE(ownf + k, t + 1);
        }
    }

    // ---- final FC (layer 3): y = fc_w . h_last + fc_b ----
    if (doFC && wave == 0) {
        float p = (lane < 16) ? fcv * hval : 0.f;
#pragma unroll
        for (int o = 8; o; o >>= 1) p += __shfl_xor(p, o);
        if (lane == 0) atomicAdd(out, p);
    }
}

__global__ __launch_bounds__(NTHR, 2) void lstm_persistent(
    const uint32_t* __restrict__ x0p,
    uint32_t* ring,
    const uint32_t* __restrict__ wp,
    const float* __restrict__ b0, const float* __restrict__ b1,
    const float* __restrict__ b2, const float* __restrict__ b3,
    const float* __restrict__ fcw, float* out,
    int* flags, int* abortf)
{
    const int bid = blockIdx.x;
    const int xcd = bid & 7;
    const int layer = xcd >> 1;                    // 2 XCDs per layer
    const int k = ((bid >> 3) << 1) | (xcd & 1);   // 0..63 within layer

    const float* bias = (layer == 0) ? b0 : (layer == 1) ? b1 : (layer == 2) ? b2 : b3;
    int* ownf = flags + layer * NCU_L;
    int* upf  = layer ? (flags + (layer - 1) * NCU_L) : nullptr;
    int* dnf  = (layer < 3) ? (flags + (layer + 1) * NCU_L) : nullptr;

    uint32_t* own_ring = ring + (size_t)layer * RING * 512;
    const uint32_t* up_ring = layer ? (ring + (size_t)(layer - 1) * RING * 512) : nullptr;
    const uint32_t* wsrc = wp + (size_t)layer * WL_DW + (size_t)k * WK_DW;

    run_layer(k, layer == 0, x0p, up_ring, own_ring, wsrc, bias, fcw, out,
              ownf, upf, dnf, abortf, layer == 3);
}

// ---------------- host launcher ----------------

extern "C" void kernel_launch(void* const* d_in, const int* in_sizes, int n_in,
                              void* d_out, int out_size, void* d_ws, size_t ws_size,
                              hipStream_t stream) {
    const float* seq  = (const float*)d_in[0];
    const float* wih0 = (const float*)d_in[1];
    const float* whh0 = (const float*)d_in[2];
    const float* b0   = (const float*)d_in[3];
    const float* wih1 = (const float*)d_in[4];
    const float* whh1 = (const float*)d_in[5];
    const float* b1   = (const float*)d_in[6];
    const float* wih2 = (const float*)d_in[7];
    const float* whh2 = (const float*)d_in[8];
    const float* b2   = (const float*)d_in[9];
    const float* wih3 = (const float*)d_in[10];
    const float* whh3 = (const float*)d_in[11];
    const float* b3   = (const float*)d_in[12];
    const float* fcw  = (const float*)d_in[13];
    const float* fcb  = (const float*)d_in[14];
    float* out = (float*)d_out;

    if (ws_size < TOTAL_WS) return;

    uint8_t* ws = (uint8_t*)d_ws;
    uint32_t* x0p  = (uint32_t*)ws;
    uint32_t* ring = (uint32_t*)(ws + X0B);
    uint32_t* wp   = (uint32_t*)(ws + X0B + RINGB);
    int* flags     = (int*)(ws + X0B + RINGB + WB);
    int* abortf    = flags + NL * NCU_L;

    conv_x_kernel<<<(int)(X0_DW / 256), 256, 0, stream>>>(seq, x0p);
    pack_weights_kernel<<<(int)(WL_DW / 256), 256, 0, stream>>>(wih0, whh0, DIN0, wp);
    pack_weights_kernel<<<(int)(WL_DW / 256), 256, 0, stream>>>(wih1, whh1, HID, wp + WL_DW);
    pack_weights_kernel<<<(int)(WL_DW / 256), 256, 0, stream>>>(wih2, whh2, HID, wp + 2 * WL_DW);
    pack_weights_kernel<<<(int)(WL_DW / 256), 256, 0, stream>>>(wih3, whh3, HID, wp + 3 * WL_DW);
    init_misc_kernel<<<(int)((FLAG_N + 255) / 256), 256, 0, stream>>>(flags, (int)FLAG_N, out, fcb);

    lstm_persistent<<<256, NTHR, 0, stream>>>(x0p, ring, wp, b0, b1, b2, b3, fcw, out, flags, abortf);
}

// Round 7
// 24933.824 us; speedup vs baseline: 7.2128x; 1.0923x over previous
//
#include <hip/hip_runtime.h>
#include <stdint.h>

// R7: (1) tagged-h ring: each h element stored as (half<<16)|(t&0xFFFF); consumers
//     poll data tags directly -> no flag round-trip; x-poll and h-poll overlap.
//     (2) gates distributed across all 8 waves (2 h-outputs/wave).
//     (3) amdgpu_waves_per_eu(2,2) pins occupancy -> 256-VGPR budget for resident
//     weights. Flags only remain as a rare ring-overrun guard.

#define S_LEN 8192
#define HID   1024
#define DIN0  256
#define NL    4
#define NCU_L 64
#define NTHR  512
#define NWAVE 8
#define SP    128          // weight dwords per lane per wave
#define RING  1024
#define RMASK (RING - 1)

typedef _Float16 half2v __attribute__((ext_vector_type(2)));
typedef uint32_t v4u   __attribute__((ext_vector_type(4)));

#if defined(__has_builtin)
#if __has_builtin(__builtin_amdgcn_fdot2)
#define HAVE_FDOT2 1
#endif
#endif

__device__ __forceinline__ float dot2acc(uint32_t w, uint32_t x, float acc) {
#ifdef HAVE_FDOT2
    return __builtin_amdgcn_fdot2(__builtin_bit_cast(half2v, w),
                                  __builtin_bit_cast(half2v, x), acc, false);
#else
    half2v hw = __builtin_bit_cast(half2v, w);
    half2v hx = __builtin_bit_cast(half2v, x);
    return acc + (float)hw.x * (float)hx.x + (float)hw.y * (float)hx.y;
#endif
}

#define ALOAD(p)      __hip_atomic_load((p), __ATOMIC_RELAXED, __HIP_MEMORY_SCOPE_AGENT)
#define ASTORE(p, v)  __hip_atomic_store((p), (v), __ATOMIC_RELAXED, __HIP_MEMORY_SCOPE_AGENT)

// ---- workspace layout ----
constexpr size_t X0_DW   = (size_t)S_LEN * (DIN0 / 2);            // 4 MB
constexpr size_t X0B     = X0_DW * 4;
constexpr size_t RING_DW = (size_t)NL * RING * HID;               // tagged dwords, 16 MB
constexpr size_t RINGB   = RING_DW * 4;
constexpr size_t WK_DW   = (size_t)NWAVE * SP * 64;               // 65536 dw per block
constexpr size_t WL_DW   = (size_t)NCU_L * WK_DW;
constexpr size_t WB      = (size_t)NL * WL_DW * 4;                // ~67 MB
constexpr size_t FLAG_N  = (size_t)NL * NCU_L + 1;                // prog[4][64] + abort
constexpr size_t TOTAL_WS = X0B + RINGB + WB + FLAG_N * 4;

// ---------------- pre-kernels ----------------

__global__ void conv_x_kernel(const float* __restrict__ x, uint32_t* __restrict__ dst) {
    int i = blockIdx.x * 256 + threadIdx.x;   // exactly X0_DW threads
    float v0 = x[2 * i], v1 = x[2 * i + 1];
    half2v h = {(_Float16)v0, (_Float16)v1};
    dst[i] = __builtin_bit_cast(uint32_t, h);
}

// dst layout: [k(64)][wave(8)][c4(32)][lane(64)][e(4)].
// Column space (halves): [0,1024) = x region (cols >= din zero-padded),
//                        [1024,2048) = h region.
__global__ void pack_weights_kernel(const float* __restrict__ wih, const float* __restrict__ whh,
                                    int din, uint32_t* __restrict__ dst) {
    int i = blockIdx.x * 256 + threadIdx.x;   // exactly WL_DW threads
    int e = i & 3;  int q = i >> 2;
    int l = q & 63; q >>= 6;
    int c4 = q & 31; q >>= 5;
    int w = q & 7;  int k = q >> 3;
    int c = 4 * c4 + e;
    int col = w * 256 + 2 * c;                // half col in [0,2048)
    int row = (l >> 4) * HID + k * 16 + (l & 15);
    float v0, v1;
    {
        int hc = col;
        v0 = (hc < 1024) ? ((hc < din) ? wih[(size_t)row * din + hc] : 0.f)
                         : whh[(size_t)row * HID + (hc - 1024)];
        hc = col + 1;
        v1 = (hc < 1024) ? ((hc < din) ? wih[(size_t)row * din + hc] : 0.f)
                         : whh[(size_t)row * HID + (hc - 1024)];
    }
    half2v h = {(_Float16)v0, (_Float16)v1};
    dst[i] = __builtin_bit_cast(uint32_t, h);
}

__global__ void init_misc_kernel(int* __restrict__ flags, int n, float* __restrict__ out,
                                 const float* __restrict__ fcb) {
    int i = blockIdx.x * 256 + threadIdx.x;
    if (i < n) flags[i] = 0;
    if (i == 0) out[0] = fcb[0];
}

// ---------------- persistent LSTM kernel ----------------

__device__ __forceinline__ float fsigmoid(float x) { return 1.f / (1.f + __expf(-x)); }
__device__ __forceinline__ float ftanh_c(float x) {
    float e = __expf(-2.f * x);
    return (1.f - e) / (1.f + e);
}

// Poll 4 consecutive tagged dwords until all carry `tag` in low 16 bits.
__device__ __forceinline__ v4u poll4(const uint32_t* p, uint32_t tag, int* abortf) {
    v4u d;
    int tries = 0;
    for (;;) {
        uint64_t a = ALOAD((const uint64_t*)p);
        uint64_t b = ALOAD((const uint64_t*)(p + 2));
        d[0] = (uint32_t)a; d[1] = (uint32_t)(a >> 32);
        d[2] = (uint32_t)b; d[3] = (uint32_t)(b >> 32);
        uint32_t bad = ((d[0] ^ tag) | (d[1] ^ tag) | (d[2] ^ tag) | (d[3] ^ tag)) & 0xFFFFu;
        if (bad == 0) break;
        if ((++tries & 255) == 0) {
            if (ALOAD(abortf)) break;
            if (tries > (1 << 22)) { ASTORE(abortf, 1); break; }
        }
    }
    return d;
}

#define REP32(M) M(0) M(1) M(2) M(3) M(4) M(5) M(6) M(7) M(8) M(9) M(10) M(11) \
                 M(12) M(13) M(14) M(15) M(16) M(17) M(18) M(19) M(20) M(21) M(22) M(23) \
                 M(24) M(25) M(26) M(27) M(28) M(29) M(30) M(31)

__device__ __forceinline__ void run_layer(
    int k, bool isL0,
    const uint32_t* __restrict__ x0p,     // layer 0 input (packed halves, untagged)
    const uint32_t* up_ring,              // upstream tagged ring (null for L0)
    uint32_t* own_ring,                   // own tagged ring
    const uint32_t* __restrict__ wsrc,
    const float* __restrict__ bias,
    const float* __restrict__ fcw,
    float* out,
    int* prog_own, int* prog_dn, int* abortf, bool doFC)
{
    __shared__ alignas(16) uint32_t in_lds[NWAVE * SP];   // 1024 dw = 4 KB
    __shared__ float red[NWAVE][65];                      // +1 pad vs bank aliasing

    const int tid  = threadIdx.x;
    const int wave = tid >> 6;
    const int lane = tid & 63;

    // ---- weight slice: 32 v4u via asm loads (non-remat); waves_per_eu(2,2)
    //      gives the 256-VGPR budget they need to stay resident.
    const uint32_t* wb = wsrc + (size_t)wave * (SP * 64) + lane * 4;
#define WLOAD(i) v4u W##i; { const uint32_t* a_ = wb + (size_t)(i) * 256;        \
        asm volatile("global_load_dwordx4 %0, %1, off\n\ts_waitcnt vmcnt(0)"     \
                     : "=v"(W##i) : "v"(a_) : "memory"); }
    REP32(WLOAD)
#undef WLOAD

    // per-lane gate-row mapping for the distributed epilogue:
    // rs=lane>>3, part=lane&7; row = 2*wave + (rs&1) + 16*(rs>>1)
    const int part = lane & 7;
    const int rs   = lane >> 3;
    const int row  = 2 * wave + (rs & 1) + 16 * (rs >> 1);
    const bool owner = ((lane & 0x37) == 0);              // lanes 0, 8
    const int hidx = k * 16 + 2 * wave + (lane >> 3);     // valid on owner lanes

    const float bval = bias[(row >> 4) * HID + k * 16 + (row & 15)];
    float fcv = 0.f;
    if (owner && doFC) fcv = fcw[hidx];
    float cst = 0.f, hval = 0.f;

    for (int t = 0; t < S_LEN; ++t) {
        const int slot = t & RMASK;

        // ---- rare ring-overrun guard (off critical path; every 64 steps) ----
        if (prog_dn && wave == 0 && t >= RING && (t & 63) == 0) {
            int it = 0;
            for (;;) {
                int ok = (ALOAD(prog_dn + lane) >= t - RING + 64);
                if (__all(ok)) break;
                if ((++it & 255) == 0) {
                    if (ALOAD(abortf)) break;
                    if (it > (1 << 22)) { ASTORE(abortf, 1); break; }
                }
            }
        }

        // ---- stage [x(512dw) | h_{t-1}(512dw)] into LDS via tagged polls ----
        {
            uint32_t dw0, dw1;
            if (tid < 256) {
                if (isL0) {
                    uint64_t v = 0;
                    if (tid < 64) v = *(const uint64_t*)(x0p + (size_t)t * 128 + 2 * tid);
                    dw0 = (uint32_t)v; dw1 = (uint32_t)(v >> 32);
                } else {
                    v4u d = poll4(up_ring + (size_t)slot * HID + 4 * tid, (uint32_t)t, abortf);
                    dw0 = (d[0] >> 16) | (d[1] & 0xFFFF0000u);
                    dw1 = (d[2] >> 16) | (d[3] & 0xFFFF0000u);
                }
            } else {
                if (t) {
                    v4u d = poll4(own_ring + (size_t)((t - 1) & RMASK) * HID + 4 * (tid - 256),
                                  (uint32_t)(t - 1), abortf);
                    dw0 = (d[0] >> 16) | (d[1] & 0xFFFF0000u);
                    dw1 = (d[2] >> 16) | (d[3] & 0xFFFF0000u);
                } else { dw0 = 0u; dw1 = 0u; }
            }
            in_lds[2 * tid] = dw0;
            in_lds[2 * tid + 1] = dw1;
        }
        __syncthreads();

        // ---- dot: lane = gate row, wave = 256-half column slice ----
        const uint32_t* wi = in_lds + wave * SP;
        float a0 = 0, a1 = 0, a2 = 0, a3 = 0;
#define DOT(i) { v4u x_ = *(const v4u*)&wi[4 * (i)];            \
        a0 = dot2acc(W##i[0], x_[0], a0);                       \
        a1 = dot2acc(W##i[1], x_[1], a1);                       \
        a2 = dot2acc(W##i[2], x_[2], a2);                       \
        a3 = dot2acc(W##i[3], x_[3], a3); }
        DOT(0) DOT(1) DOT(2) DOT(3)
        __builtin_amdgcn_sched_barrier(0);
        DOT(4) DOT(5) DOT(6) DOT(7)
        __builtin_amdgcn_sched_barrier(0);
        DOT(8) DOT(9) DOT(10) DOT(11)
        __builtin_amdgcn_sched_barrier(0);
        DOT(12) DOT(13) DOT(14) DOT(15)
        __builtin_amdgcn_sched_barrier(0);
        DOT(16) DOT(17) DOT(18) DOT(19)
        __builtin_amdgcn_sched_barrier(0);
        DOT(20) DOT(21) DOT(22) DOT(23)
        __builtin_amdgcn_sched_barrier(0);
        DOT(24) DOT(25) DOT(26) DOT(27)
        __builtin_amdgcn_sched_barrier(0);
        DOT(28) DOT(29) DOT(30) DOT(31)
#undef DOT
        red[wave][lane] = (a0 + a1) + (a2 + a3);
        __syncthreads();

        // ---- distributed epilogue: each wave finalizes 2 h-outputs ----
        {
            float p = red[part][row];
            p += __shfl_xor(p, 1);
            p += __shfl_xor(p, 2);
            p += __shfl_xor(p, 4);
            p += bval;
            p = fminf(15.f, fmaxf(-15.f, p));
            float pf = __shfl(p, (lane + 16) & 63);
            float pg = __shfl(p, (lane + 32) & 63);
            float po = __shfl(p, (lane + 48) & 63);
            if (owner) {
                float ig = fsigmoid(p);
                float fg = fsigmoid(pf);
                float gg = ftanh_c(pg);
                float og = fsigmoid(po);
                cst = fg * cst + ig * gg;
                float c2 = fminf(15.f, fmaxf(-15.f, cst));
                hval = og * ftanh_c(c2);
                uint32_t hb = (uint32_t)__builtin_bit_cast(unsigned short, (_Float16)hval);
                ASTORE(own_ring + (size_t)slot * HID + hidx, (hb << 16) | ((uint32_t)t & 0xFFFFu));
            }
        }

        if (((t & 63) == 63) && tid == 0) ASTORE(prog_own + k, t);
    }

    // ---- final FC (layer 3): y = fc_w . h_last + fc_b ----
    if (doFC) {
        float p = owner ? fcv * hval : 0.f;
#pragma unroll
        for (int o = 32; o; o >>= 1) p += __shfl_xor(p, o);
        if (lane == 0) atomicAdd(out, p);
    }
}

__global__ __launch_bounds__(NTHR, 2) __attribute__((amdgpu_waves_per_eu(2, 2)))
void lstm_persistent(
    const uint32_t* __restrict__ x0p,
    uint32_t* ring,
    const uint32_t* __restrict__ wp,
    const float* __restrict__ b0, const float* __restrict__ b1,
    const float* __restrict__ b2, const float* __restrict__ b3,
    const float* __restrict__ fcw, float* out,
    int* flags, int* abortf)
{
    const int bid = blockIdx.x;
    const int xcd = bid & 7;
    const int layer = xcd >> 1;                    // 2 XCDs per layer
    const int k = ((bid >> 3) << 1) | (xcd & 1);   // 0..63 within layer

    const float* bias = (layer == 0) ? b0 : (layer == 1) ? b1 : (layer == 2) ? b2 : b3;
    int* prog_own = flags + layer * NCU_L;
    int* prog_dn  = (layer < 3) ? (flags + (layer + 1) * NCU_L) : nullptr;

    uint32_t* own_ring = ring + (size_t)layer * RING * HID;
    const uint32_t* up_ring = layer ? (ring + (size_t)(layer - 1) * RING * HID) : nullptr;
    const uint32_t* wsrc = wp + (size_t)layer * WL_DW + (size_t)k * WK_DW;

    run_layer(k, layer == 0, x0p, up_ring, own_ring, wsrc, bias, fcw, out,
              prog_own, prog_dn, abortf, layer == 3);
}

// ---------------- host launcher ----------------

extern "C" void kernel_launch(void* const* d_in, const int* in_sizes, int n_in,
                              void* d_out, int out_size, void* d_ws, size_t ws_size,
                              hipStream_t stream) {
    const float* seq  = (const float*)d_in[0];
    const float* wih0 = (const float*)d_in[1];
    const float* whh0 = (const float*)d_in[2];
    const float* b0   = (const float*)d_in[3];
    const float* wih1 = (const float*)d_in[4];
    const float* whh1 = (const float*)d_in[5];
    const float* b1   = (const float*)d_in[6];
    const float* wih2 = (const float*)d_in[7];
    const float* whh2 = (const float*)d_in[8];
    const float* b2   = (const float*)d_in[9];
    const float* wih3 = (const float*)d_in[10];
    const float* whh3 = (const float*)d_in[11];
    const float* b3   = (const float*)d_in[12];
    const float* fcw  = (const float*)d_in[13];
    const float* fcb  = (const float*)d_in[14];
    float* out = (float*)d_out;

    if (ws_size < TOTAL_WS) return;

    uint8_t* ws = (uint8_t*)d_ws;
    uint32_t* x0p  = (uint32_t*)ws;
    uint32_t* ring = (uint32_t*)(ws + X0B);
    uint32_t* wp   = (uint32_t*)(ws + X0B + RINGB);
    int* flags     = (int*)(ws + X0B + RINGB + WB);
    int* abortf    = flags + NL * NCU_L;

    conv_x_kernel<<<(int)(X0_DW / 256), 256, 0, stream>>>(seq, x0p);
    pack_weights_kernel<<<(int)(WL_DW / 256), 256, 0, stream>>>(wih0, whh0, DIN0, wp);
    pack_weights_kernel<<<(int)(WL_DW / 256), 256, 0, stream>>>(wih1, whh1, HID, wp + WL_DW);
    pack_weights_kernel<<<(int)(WL_DW / 256), 256, 0, stream>>>(wih2, whh2, HID, wp + 2 * WL_DW);
    pack_weights_kernel<<<(int)(WL_DW / 256), 256, 0, stream>>>(wih3, whh3, HID, wp + 3 * WL_DW);
    init_misc_kernel<<<(int)((FLAG_N + 255) / 256), 256, 0, stream>>>(flags, (int)FLAG_N, out, fcb);

    lstm_persistent<<<256, NTHR, 0, stream>>>(x0p, ring, wp, b0, b1, b2, b3, fcw, out, flags, abortf);
}